// Round 4
// baseline (188.105 us; speedup 1.0000x reference)
//
#include <hip/hip_runtime.h>

// Problem constants (fixed by reference)
#define CI    16
#define CO    16
#define HID   256
#define KPAD  288    // 256 + 32; k==256 row carries b2 (VALU-free bias), rest 0
#define NKK   9      // KPAD/32 MFMA K-steps (B side; W2b layout)
#define NKH   8      // kk frags held in LDS (kk=8 pad frag synthesized in regs)
#define NCH   144    // CI*9 columns per output channel
#define IMGH  128
#define IMGW  128
#define NMS   8      // M=128 px per block -> 8 ms-tiles of 16 (4 per m-group)
#define RSTR  132    // shPatch row stride in SHORTS (264 B, 8B-aligned)
#define RLEN  130    // valid window px per row: 128 + 2 halo
#define KKSTR (NCH * 32)        // shorts per kk block  = 4608
#define OSTRS (NKK * NCH * 32)  // shorts per o         = 41472
#define MGOFF (4 * NKH * 512)   // shHf shorts per m-group = 16384

typedef float f32x4  __attribute__((ext_vector_type(4)));
typedef float f32x2  __attribute__((ext_vector_type(2)));
typedef short bf16x8 __attribute__((ext_vector_type(8)));

__device__ __host__ __forceinline__ short f2bf(float f) {
  union { float f; unsigned u; } c; c.f = f;
  unsigned b = c.u + 0x7FFFu + ((c.u >> 16) & 1u);   // RNE
  return (short)(b >> 16);
}

// ---------------------------------------------------------------------------
// Prep: W2 [256][2304] fp32 (+ b2[2304]) -> W2b [o][kk:9][n':144][k:32] bf16,
// K padded to 288 (row 256 = b2, rows 257..287 = 0).
// n-columns permuted dx-MAJOR: n' = dx*48 + i*3 + dyr -> dx is uniform per
// 16-wide n-tile, so the main kernel's patch contraction reads an aligned
// window with a per-pass constant shift. Contraction sums over n: order free.
// grid = 36 col-blocks * 9 kk = 324 blocks x 256 threads.
// ---------------------------------------------------------------------------
__global__ void prep_w2(const float* __restrict__ W2, const float* __restrict__ b2,
                        short* __restrict__ W2b) {
  __shared__ float tile[32][65];
  const int kk = blockIdx.x % NKK;
  const int colbase = (blockIdx.x / NKK) * 64;
  const int tid = threadIdx.x;

  for (int e = tid; e < 2048; e += 256) {
    int klr = e >> 6;          // 0..31
    int cc  = e & 63;
    int col = colbase + cc;
    float v;
    if (kk < 8) v = W2[(kk * 32 + klr) * (CO * NCH) + col];
    else        v = (klr == 0) ? b2[col] : 0.f;
    tile[klr][cc] = v;
  }
  __syncthreads();
  for (int e = tid; e < 2048; e += 256) {
    int cc = e >> 5;           // 0..63
    int kl = e & 31;
    int col = colbase + cc;
    int o = col / NCH;
    int n = col - o * NCH;
    int i = n / 9, q = n - i * 9;
    int dyr = q / 3, dx = q - dyr * 3;
    int np = dx * 48 + i * 3 + dyr;            // dx-major permutation
    W2b[(((o * NKK + kk) * NCH + np) << 5) + kl] = f2bf(tile[kl][cc]);
  }
}

// ---------------------------------------------------------------------------
// Main fused kernel, v15 (resubmit; R3 was an infra failure, no counters):
// same per-block work as v14 (M=128, one full image row, grid 512), but
// 512 THREADS / 8 WAVES per block.
// Post-mortem of v14 (96.7 us): MFMA pipe 43%, LDS pipe ~41%, VALU 30% —
// no pipe saturated, wall = 2.3x max pipe. Classic in-wave dependency-chain
// serialization (ds_read -> MFMA -> epilogue VALU) with only 2 waves/SIMD to
// fill the gaps. v15 keeps per-CU totals IDENTICAL and doubles waves/SIMD:
// wave w owns m-group mg=w>>2 (64 px) and channels {w&3,+4,+8,+12}.
// Per-wave regs drop to the v12 budget (acc[4][3]+P2[8]+B ~ 110) so
// __launch_bounds__(512,4)'s 128-VGPR cap holds -> 2 blocks/CU = 16 waves.
// mg-pair waves read identical B streams near-simultaneously on one CU ->
// second read hits L1/L2 (no extra HBM).
// LDS: shHf 65.5 KB + shPatch 12.7 KB = 78.2 KB -> 2 blocks/CU exactly.
// grid = 4 batches * 128 rows = 512 blocks x 512 threads.
// ---------------------------------------------------------------------------
__global__ __launch_bounds__(512, 4)
void ngconv_main(const float* __restrict__ in, const float* __restrict__ foa,
                 const float* __restrict__ W1, const float* __restrict__ b1,
                 const short* __restrict__ W2b, float* __restrict__ out) {
  __shared__ short shHf[64 * 512];        // 64 frags (msG 0..7, kk 0..7) = 65.5 KB
  __shared__ short shPatch[48 * RSTR];    // raw rows [i*3+dyr][xx] bf16, 12.7 KB

  const int tid  = threadIdx.x;
  const int lane = tid & 63;
  const int wv8  = tid >> 6;        // 0..7
  const int mg   = wv8 >> 2;        // m-group: px 0..63 or 64..127
  const int wo   = wv8 & 3;         // channel group
  const int c15  = lane & 15;
  const int quad = lane >> 4;

  const int blk = blockIdx.x;
  const int b   = blk >> 7;
  const int y   = blk & 127;

  const float fx  = foa[b * 2 + 0];
  const float fy  = foa[b * 2 + 1];
  const float dyv = (float)y - fy;

  const int ry0 = (y == 0) ? 1 : (y - 1);
  const int ry2 = (y == IMGH - 1) ? (IMGH - 2) : (y + 1);

  // ---- shPatch[r=i*3+dyr][xx]: reflect-extended row, xx in [0,130) maps to
  // image x = xx - 1. Patch value for (n'=(dx,i,dyr), px) = row[px+dx].
  for (int e = tid; e < 48 * RLEN; e += 512) {
    int r  = e / RLEN;                // 0..47 = i*3 + dyr
    int xx = e - r * RLEN;
    int i = r / 3, dyr = r - i * 3;
    int ryr = (dyr == 0) ? ry0 : ((dyr == 1) ? y : ry2);
    int x = xx - 1;
    x = (x < 0) ? 1 : ((x > IMGW - 1) ? (IMGW - 2) : x);   // reflect
    shPatch[r * RSTR + xx] = f2bf(in[((b * CI + i) * IMGH + ryr) * IMGW + x]);
  }

  // ---- shHf: H in fragment order, kk=0..7. frag(msG,kk) = A[16px][32k];
  // lane slot (c15=px, quad=k-octet). 128 px x 32 k-slots = 4096 = 8 exact its.
  for (int g = tid; g < 128 * 32; g += 512) {
    int px = g & 127;
    int ks = g >> 7;                  // 0..31 -> k0 = ks*8 < 256
    int k0 = ks << 3;
    float dxv = (float)px - fx;
    short hv[8];
    #pragma unroll
    for (int j = 0; j < 8; ++j) {
      int k = k0 + j;
      float h = fmaxf(fmaf(dxv, W1[k], fmaf(dyv, W1[HID + k], b1[k])), 0.f);
      hv[j] = f2bf(h);
    }
    int ms = px >> 4;                 // 0..7 (msG)
    int kk = k0 >> 5;
    int lslot = ((k0 & 31) >> 3) * 16 + (px & 15);   // quad*16 + c15
    *(bf16x8*)&shHf[((ms * NKH + kk) << 9) + (lslot << 3)] = *(bf16x8*)hv;
  }

  // ---- kk=8 pad fragment, constant, in registers: k=256 -> 1.0 (b2 row)
  bf16x8 af8 = (bf16x8){0, 0, 0, 0, 0, 0, 0, 0};
  if (quad == 0) af8[0] = (short)0x3F80;   // bf16 1.0

  __syncthreads();

  // ---- main loop: 4 output channels per wave, N in three passes of 3
  const short* shHg = shHf + mg * MGOFF;   // this wave's 4 ms-tiles

  #pragma unroll 1
  for (int oj = 0; oj < 4; ++oj) {
    const int o = wo + oj * 4;
    const short* Bo = W2b + o * OSTRS + (c15 << 5) + (quad << 3);

    // per-oj partial sums (accumulate across all 3 passes; tree at the end)
    f32x2 P2[8];
    #pragma unroll
    for (int t = 0; t < 8; ++t) P2[t] = (f32x2){0.f, 0.f};

    #pragma unroll 1
    for (int pass = 0; pass < 3; ++pass) {
      const short* Bp = Bo + (pass * 3) * 512;   // first n-tile of this pass
      f32x4 acc[4][3];
      #pragma unroll
      for (int ms = 0; ms < 4; ++ms)
        #pragma unroll
        for (int j = 0; j < 3; ++j)
          acc[ms][j] = (f32x4){0.f, 0.f, 0.f, 0.f};

      // copy-free 2-buffer ping-pong, distance-1 prefetch, explicit tail.
      bf16x8 bE[3], bO[3];
      #pragma unroll
      for (int j = 0; j < 3; ++j) bE[j] = *(const bf16x8*)&Bp[j << 9];

      #pragma unroll 1
      for (int t = 0; t < 4; ++t) {
        const int kkE = 2 * t;            // even kk, uses bE
        #pragma unroll
        for (int j = 0; j < 3; ++j)       // prefetch odd kk into bO
          bO[j] = *(const bf16x8*)&Bp[(kkE + 1) * KKSTR + (j << 9)];
        {
          const short* hp = shHg + (kkE << 9) + (lane << 3);
          #pragma unroll
          for (int ms = 0; ms < 4; ++ms) {
            bf16x8 af = *(const bf16x8*)&hp[ms * (NKH << 9)];
            #pragma unroll
            for (int j = 0; j < 3; ++j)
              acc[ms][j] = __builtin_amdgcn_mfma_f32_16x16x32_bf16(
                  af, bE[j], acc[ms][j], 0, 0, 0);
          }
        }
        #pragma unroll
        for (int j = 0; j < 3; ++j)       // prefetch next even kk into bE
          bE[j] = *(const bf16x8*)&Bp[(kkE + 2) * KKSTR + (j << 9)];
        {
          const short* hp = shHg + ((kkE + 1) << 9) + (lane << 3);
          #pragma unroll
          for (int ms = 0; ms < 4; ++ms) {
            bf16x8 af = *(const bf16x8*)&hp[ms * (NKH << 9)];
            #pragma unroll
            for (int j = 0; j < 3; ++j)
              acc[ms][j] = __builtin_amdgcn_mfma_f32_16x16x32_bf16(
                  af, bO[j], acc[ms][j], 0, 0, 0);
          }
        }
      }
      {   // tail kk=8 (b2 K-row): af8 from registers, B already in bE
        #pragma unroll
        for (int ms = 0; ms < 4; ++ms)
          #pragma unroll
          for (int j = 0; j < 3; ++j)
            acc[ms][j] = __builtin_amdgcn_mfma_f32_16x16x32_bf16(
                af8, bE[j], acc[ms][j], 0, 0, 0);
      }

      // ---- per-pass patch contraction into P2 (b2 already in acc).
      // n' = (pass*3+j)*16 + c15 is dx-major: dx == pass (wave-uniform),
      // row index = 16*j + c15, window = row[mg*64 + ms*16 + quad*4 + dx ..].
      // Aligned reads (b64 + b32) + two uniform 64-bit shifts.
      const int sh = pass << 4;          // 0 / 16 / 32 bits
      #pragma unroll
      for (int j = 0; j < 3; ++j) {
        const short* prow = &shPatch[((j << 4) + c15) * RSTR + (mg << 6) + (quad << 2)];
        #pragma unroll
        for (int ms = 0; ms < 4; ++ms) {
          uint2 u0 = *(const uint2*)&prow[ms * 16];           // ds_read_b64
          unsigned u1 = *(const unsigned*)&prow[ms * 16 + 4]; // ds_read_b32
          unsigned long long a0 =
              (unsigned long long)u0.x | ((unsigned long long)u0.y << 32);
          unsigned long long a1 =
              (unsigned long long)u0.y | ((unsigned long long)u1 << 32);
          unsigned d0 = (unsigned)(a0 >> sh);                // taps r=0,1
          unsigned d1 = (unsigned)(a1 >> sh);                // taps r=2,3
          float p0 = __uint_as_float(d0 << 16);
          float p1 = __uint_as_float(d0 & 0xFFFF0000u);
          float p2 = __uint_as_float(d1 << 16);
          float p3 = __uint_as_float(d1 & 0xFFFF0000u);
          f32x2 a01 = {acc[ms][j][0], acc[ms][j][1]};
          f32x2 a23 = {acc[ms][j][2], acc[ms][j][3]};
          P2[ms * 2 + 0] += a01 * (f32x2){p0, p1};           // v_pk_fma_f32
          P2[ms * 2 + 1] += a23 * (f32x2){p2, p3};
        }
      }
    }

    // ---- ONE reduce-scatter tree per oj.
    // final P[0] at lane = column sum for px = mg*64 + (c15>>2)*16 + quad*4 + (c15&3)
    float P[16];
    #pragma unroll
    for (int t = 0; t < 16; ++t) P[t] = P2[t >> 1][t & 1];
    #pragma unroll
    for (int m = 8; m >= 1; m >>= 1) {
      const bool hi = (c15 & m) != 0;
      #pragma unroll
      for (int j = 0; j < m; ++j) {
        float keep = hi ? P[j + m] : P[j];
        float send = hi ? P[j] : P[j + m];
        float recv = __shfl_xor(send, m, 64);
        P[j] = keep + recv;
      }
    }

    const int x = (mg << 6) + (c15 >> 2) * 16 + quad * 4 + (c15 & 3);
    out[((b * CO + o) * IMGH + y) * IMGW + x] = P[0];
  }
}

// ---------------------------------------------------------------------------
extern "C" void kernel_launch(void* const* d_in, const int* in_sizes, int n_in,
                              void* d_out, int out_size, void* d_ws, size_t ws_size,
                              hipStream_t stream) {
  const float* in  = (const float*)d_in[0];   // [4,16,128,128]
  const float* foa = (const float*)d_in[1];   // [4,2]
  const float* W1  = (const float*)d_in[2];   // [2,256]
  const float* b1  = (const float*)d_in[3];   // [256]
  const float* W2  = (const float*)d_in[4];   // [256,2304]
  const float* b2  = (const float*)d_in[5];   // [2304]
  float* out = (float*)d_out;
  short* W2b = (short*)d_ws;                  // 16*9*144*32 bf16 = 1.33 MB

  prep_w2<<<324, 256, 0, stream>>>(W2, b2, W2b);
  ngconv_main<<<512, 512, 0, stream>>>(in, foa, W1, b1, W2b, out);
}

// Round 5
// 158.623 us; speedup vs baseline: 1.1859x; 1.1859x over previous
//
#include <hip/hip_runtime.h>

// Problem constants (fixed by reference)
#define CI    16
#define CO    16
#define HID   256
#define KPAD  288    // 256 + 32; k==256 row carries b2 (VALU-free bias), rest 0
#define NKK   9      // KPAD/32 MFMA K-steps (B side; W2b layout)
#define NKH   8      // kk frags held in LDS (kk=8 pad frag synthesized in regs)
#define NCH   144    // CI*9 columns per output channel
#define IMGH  128
#define IMGW  128
#define RSTR  132    // shPatch row stride in SHORTS (264 B, 8B-aligned)
#define RLEN  130    // valid window px per row: 128 + 2 halo
#define KKSTR (NCH * 32)        // shorts per kk block  = 4608
#define OSTRS (NKK * NCH * 32)  // shorts per o         = 41472
#define MGOFF (4 * NKH * 512)   // shHf shorts per m-group = 16384

typedef float f32x4  __attribute__((ext_vector_type(4)));
typedef float f32x2  __attribute__((ext_vector_type(2)));
typedef short bf16x8 __attribute__((ext_vector_type(8)));

__device__ __host__ __forceinline__ short f2bf(float f) {
  union { float f; unsigned u; } c; c.f = f;
  unsigned b = c.u + 0x7FFFu + ((c.u >> 16) & 1u);   // RNE
  return (short)(b >> 16);
}

// ---------------------------------------------------------------------------
// Prep: W2 [256][2304] fp32 (+ b2[2304]) -> W2b [o][kk:9][n':144][k:32] bf16,
// K padded to 288 (row 256 = b2, rows 257..287 = 0).
// n-columns permuted dx-MAJOR: n' = dx*48 + i*3 + dyr -> dx is uniform per
// 16-wide n-tile, so the main kernel's patch contraction reads an aligned
// window with a per-pass constant shift. Contraction sums over n: order free.
// grid = 36 col-blocks * 9 kk = 324 blocks x 256 threads.
// ---------------------------------------------------------------------------
__global__ void prep_w2(const float* __restrict__ W2, const float* __restrict__ b2,
                        short* __restrict__ W2b) {
  __shared__ float tile[32][65];
  const int kk = blockIdx.x % NKK;
  const int colbase = (blockIdx.x / NKK) * 64;
  const int tid = threadIdx.x;

  for (int e = tid; e < 2048; e += 256) {
    int klr = e >> 6;          // 0..31
    int cc  = e & 63;
    int col = colbase + cc;
    float v;
    if (kk < 8) v = W2[(kk * 32 + klr) * (CO * NCH) + col];
    else        v = (klr == 0) ? b2[col] : 0.f;
    tile[klr][cc] = v;
  }
  __syncthreads();
  for (int e = tid; e < 2048; e += 256) {
    int cc = e >> 5;           // 0..63
    int kl = e & 31;
    int col = colbase + cc;
    int o = col / NCH;
    int n = col - o * NCH;
    int i = n / 9, q = n - i * 9;
    int dyr = q / 3, dx = q - dyr * 3;
    int np = dx * 48 + i * 3 + dyr;            // dx-major permutation
    W2b[(((o * NKK + kk) * NCH + np) << 5) + kl] = f2bf(tile[kl][cc]);
  }
}

// ---------------------------------------------------------------------------
// Main fused kernel, v16 = v14 shell (M=128 one full row, 256 thr, 2 blk/CU)
// + N-BLOCKING: each wave computes TWO output channels per K-sweep.
// Post-mortem v14 (96.7 us): LDS pipe was the LARGEST (~46 us: 6912
// ds_read_b128/CU for A-frags re-read once per channel), MFMA 42 us,
// VALU 29 us. v15 (8 waves) refuted the occupancy theory: VGPR cap 64
// killed per-wave ILP and 16 streams/CU + split half-row writes blew up
// FETCH/WRITE (52/48 MB vs 15.5/12.4).
// v16: wave = (wo=wv>>1, mg=wv&1); mg owns 64 px (4 ms-tiles), wo owns 8
// channels in 4 sweeps of NO=2. Per kk-step: 4 A-reads feed 24 MFMAs
// (2x fewer A-reads/MFMA); epilogue patch reads are o-independent ->
// shared across the pair (2x fewer). LDS pipe ~46 -> ~29 us; MFMA (42 us)
// becomes the dominant pipe. Distinct B streams/CU: 4 (mg-pairs coalesce).
// Writes: per-sweep staging in 2 KB LDS, flushed as full 512B rows
// (v13/v15 showed split half-row writes cost 4x WRITE amplification).
// LDS 64+12.4+2 KB = 80256 B <= 81920 -> 2 blocks/CU exactly.
// grid = 4 batches * 128 rows = 512 blocks x 256 threads.
// ---------------------------------------------------------------------------
__global__ __launch_bounds__(256, 2)
void ngconv_main(const float* __restrict__ in, const float* __restrict__ foa,
                 const float* __restrict__ W1, const float* __restrict__ b1,
                 const short* __restrict__ W2b, float* __restrict__ out) {
  __shared__ short shHf[64 * 512];        // 64 frags (ms 0..7, kk 0..7) = 64 KB
  __shared__ short shPatch[48 * RSTR];    // raw rows [i*3+dyr][xx] bf16, 12.4 KB
  __shared__ float shOut[4 * IMGW];       // per-sweep output staging, 2 KB

  const int tid  = threadIdx.x;
  const int lane = tid & 63;
  const int wv   = tid >> 6;        // 0..3
  const int wo   = wv >> 1;         // channel group: o in [wo*8, wo*8+8)
  const int mg   = wv & 1;          // m-group: px 0..63 or 64..127
  const int c15  = lane & 15;
  const int quad = lane >> 4;

  const int blk = blockIdx.x;
  const int b   = blk >> 7;
  const int y   = blk & 127;

  const float fx  = foa[b * 2 + 0];
  const float fy  = foa[b * 2 + 1];
  const float dyv = (float)y - fy;

  const int ry0 = (y == 0) ? 1 : (y - 1);
  const int ry2 = (y == IMGH - 1) ? (IMGH - 2) : (y + 1);

  // ---- shPatch[r=i*3+dyr][xx]: reflect-extended row, xx in [0,130) maps to
  // image x = xx - 1. Patch value for (n'=(dx,i,dyr), px) = row[px+dx].
  for (int e = tid; e < 48 * RLEN; e += 256) {
    int r  = e / RLEN;                // 0..47 = i*3 + dyr
    int xx = e - r * RLEN;
    int i = r / 3, dyr = r - i * 3;
    int ryr = (dyr == 0) ? ry0 : ((dyr == 1) ? y : ry2);
    int x = xx - 1;
    x = (x < 0) ? 1 : ((x > IMGW - 1) ? (IMGW - 2) : x);   // reflect
    shPatch[r * RSTR + xx] = f2bf(in[((b * CI + i) * IMGH + ryr) * IMGW + x]);
  }

  // ---- shHf: H in fragment order, kk=0..7. frag(ms,kk) = A[16px][32k];
  // lane slot (c15=px, quad=k-octet). 128 px x 32 k-slots = 4096 = 16 exact its.
  for (int g = tid; g < 128 * 32; g += 256) {
    int px = g & 127;
    int ks = g >> 7;                  // 0..31 -> k0 = ks*8 < 256
    int k0 = ks << 3;
    float dxv = (float)px - fx;
    short hv[8];
    #pragma unroll
    for (int j = 0; j < 8; ++j) {
      int k = k0 + j;
      float h = fmaxf(fmaf(dxv, W1[k], fmaf(dyv, W1[HID + k], b1[k])), 0.f);
      hv[j] = f2bf(h);
    }
    int ms = px >> 4;                 // 0..7
    int kk = k0 >> 5;
    int lslot = ((k0 & 31) >> 3) * 16 + (px & 15);   // quad*16 + c15
    *(bf16x8*)&shHf[((ms * NKH + kk) << 9) + (lslot << 3)] = *(bf16x8*)hv;
  }

  // ---- kk=8 pad fragment, constant, in registers: k=256 -> 1.0 (b2 row)
  bf16x8 af8 = (bf16x8){0, 0, 0, 0, 0, 0, 0, 0};
  if (quad == 0) af8[0] = (short)0x3F80;   // bf16 1.0

  __syncthreads();

  // ---- main loop: 4 sweeps of 2 channels per wave
  const short* shHg = shHf + mg * MGOFF;   // this wave's 4 ms-tiles

  #pragma unroll 1
  for (int s = 0; s < 4; ++s) {
    const int o0 = wo * 8 + 2 * s;
    const short* Bo0 = W2b + o0 * OSTRS + (c15 << 5) + (quad << 3);

    // per-sweep partial sums [oi][ms*2 + halfword-pair]
    f32x2 P2[2][8];
    #pragma unroll
    for (int oi = 0; oi < 2; ++oi)
      #pragma unroll
      for (int t = 0; t < 8; ++t) P2[oi][t] = (f32x2){0.f, 0.f};

    #pragma unroll 1
    for (int pass = 0; pass < 3; ++pass) {
      const short* Bp0 = Bo0 + (pass * 3) * 512;   // first n-tile, channel o0
      const short* Bp1 = Bp0 + OSTRS;              // channel o0+1
      f32x4 acc[2][4][3];
      #pragma unroll
      for (int oi = 0; oi < 2; ++oi)
        #pragma unroll
        for (int ms = 0; ms < 4; ++ms)
          #pragma unroll
          for (int j = 0; j < 3; ++j)
            acc[oi][ms][j] = (f32x4){0.f, 0.f, 0.f, 0.f};

      // copy-free 2-buffer ping-pong, distance-1 prefetch, explicit tail.
      bf16x8 bE[2][3], bO[2][3];
      #pragma unroll
      for (int j = 0; j < 3; ++j) {
        bE[0][j] = *(const bf16x8*)&Bp0[j << 9];
        bE[1][j] = *(const bf16x8*)&Bp1[j << 9];
      }

      #pragma unroll 1
      for (int t = 0; t < 4; ++t) {
        const int kkE = 2 * t;            // even kk, uses bE
        #pragma unroll
        for (int j = 0; j < 3; ++j) {     // prefetch odd kk into bO
          bO[0][j] = *(const bf16x8*)&Bp0[(kkE + 1) * KKSTR + (j << 9)];
          bO[1][j] = *(const bf16x8*)&Bp1[(kkE + 1) * KKSTR + (j << 9)];
        }
        {
          const short* hp = shHg + (kkE << 9) + (lane << 3);
          #pragma unroll
          for (int ms = 0; ms < 4; ++ms) {
            bf16x8 af = *(const bf16x8*)&hp[ms * (NKH << 9)];
            #pragma unroll
            for (int oi = 0; oi < 2; ++oi)
              #pragma unroll
              for (int j = 0; j < 3; ++j)
                acc[oi][ms][j] = __builtin_amdgcn_mfma_f32_16x16x32_bf16(
                    af, bE[oi][j], acc[oi][ms][j], 0, 0, 0);
          }
        }
        #pragma unroll
        for (int j = 0; j < 3; ++j) {     // prefetch next even kk into bE
          bE[0][j] = *(const bf16x8*)&Bp0[(kkE + 2) * KKSTR + (j << 9)];
          bE[1][j] = *(const bf16x8*)&Bp1[(kkE + 2) * KKSTR + (j << 9)];
        }
        {
          const short* hp = shHg + ((kkE + 1) << 9) + (lane << 3);
          #pragma unroll
          for (int ms = 0; ms < 4; ++ms) {
            bf16x8 af = *(const bf16x8*)&hp[ms * (NKH << 9)];
            #pragma unroll
            for (int oi = 0; oi < 2; ++oi)
              #pragma unroll
              for (int j = 0; j < 3; ++j)
                acc[oi][ms][j] = __builtin_amdgcn_mfma_f32_16x16x32_bf16(
                    af, bO[oi][j], acc[oi][ms][j], 0, 0, 0);
          }
        }
      }
      {   // tail kk=8 (b2 K-row): af8 from registers, B already in bE
        #pragma unroll
        for (int ms = 0; ms < 4; ++ms)
          #pragma unroll
          for (int oi = 0; oi < 2; ++oi)
            #pragma unroll
            for (int j = 0; j < 3; ++j)
              acc[oi][ms][j] = __builtin_amdgcn_mfma_f32_16x16x32_bf16(
                  af8, bE[oi][j], acc[oi][ms][j], 0, 0, 0);
      }

      // ---- per-pass patch contraction into P2 (b2 already in acc).
      // n' = (pass*3+j)*16 + c15 is dx-major: dx == pass (wave-uniform),
      // row index = 16*j + c15, window = row[mg*64 + ms*16 + quad*4 + dx ..].
      // Patch value is o-INDEPENDENT: one read+unpack serves both channels.
      const int sh = pass << 4;          // 0 / 16 / 32 bits
      #pragma unroll
      for (int j = 0; j < 3; ++j) {
        const short* prow = &shPatch[((j << 4) + c15) * RSTR + (mg << 6) + (quad << 2)];
        #pragma unroll
        for (int ms = 0; ms < 4; ++ms) {
          uint2 u0 = *(const uint2*)&prow[ms * 16];           // ds_read_b64
          unsigned u1 = *(const unsigned*)&prow[ms * 16 + 4]; // ds_read_b32
          unsigned long long a0 =
              (unsigned long long)u0.x | ((unsigned long long)u0.y << 32);
          unsigned long long a1 =
              (unsigned long long)u0.y | ((unsigned long long)u1 << 32);
          unsigned d0 = (unsigned)(a0 >> sh);                // taps r=0,1
          unsigned d1 = (unsigned)(a1 >> sh);                // taps r=2,3
          float p0 = __uint_as_float(d0 << 16);
          float p1 = __uint_as_float(d0 & 0xFFFF0000u);
          float p2 = __uint_as_float(d1 << 16);
          float p3 = __uint_as_float(d1 & 0xFFFF0000u);
          #pragma unroll
          for (int oi = 0; oi < 2; ++oi) {
            f32x2 a01 = {acc[oi][ms][j][0], acc[oi][ms][j][1]};
            f32x2 a23 = {acc[oi][ms][j][2], acc[oi][ms][j][3]};
            P2[oi][ms * 2 + 0] += a01 * (f32x2){p0, p1};     // v_pk_fma_f32
            P2[oi][ms * 2 + 1] += a23 * (f32x2){p2, p3};
          }
        }
      }
    }

    // ---- reduce-scatter tree per channel, stage into shOut
    #pragma unroll
    for (int oi = 0; oi < 2; ++oi) {
      float P[16];
      #pragma unroll
      for (int t = 0; t < 16; ++t) P[t] = P2[oi][t >> 1][t & 1];
      #pragma unroll
      for (int m = 8; m >= 1; m >>= 1) {
        const bool hi = (c15 & m) != 0;
        #pragma unroll
        for (int j = 0; j < m; ++j) {
          float keep = hi ? P[j + m] : P[j];
          float send = hi ? P[j] : P[j + m];
          float recv = __shfl_xor(send, m, 64);
          P[j] = keep + recv;
        }
      }
      const int px = (mg << 6) + (c15 >> 2) * 16 + quad * 4 + (c15 & 3);
      shOut[(wo * 2 + oi) * IMGW + px] = P[0];
    }
    __syncthreads();
    {   // flush 4 full rows (2 wo x 2 oi) as contiguous 512B stores
      int r  = tid >> 6;                 // 0..3 = wo*2 + oi
      int c2 = tid & 63;                 // float2 index
      int o  = (r >> 1) * 8 + 2 * s + (r & 1);
      float2 v = *(const float2*)&shOut[r * IMGW + c2 * 2];
      *(float2*)&out[((b * CO + o) * IMGH + y) * IMGW + c2 * 2] = v;
    }
    __syncthreads();
  }
}

// ---------------------------------------------------------------------------
extern "C" void kernel_launch(void* const* d_in, const int* in_sizes, int n_in,
                              void* d_out, int out_size, void* d_ws, size_t ws_size,
                              hipStream_t stream) {
  const float* in  = (const float*)d_in[0];   // [4,16,128,128]
  const float* foa = (const float*)d_in[1];   // [4,2]
  const float* W1  = (const float*)d_in[2];   // [2,256]
  const float* b1  = (const float*)d_in[3];   // [256]
  const float* W2  = (const float*)d_in[4];   // [256,2304]
  const float* b2  = (const float*)d_in[5];   // [2304]
  float* out = (float*)d_out;
  short* W2b = (short*)d_ws;                  // 16*9*144*32 bf16 = 1.33 MB

  prep_w2<<<324, 256, 0, stream>>>(W2, b2, W2b);
  ngconv_main<<<512, 256, 0, stream>>>(in, foa, W1, b1, W2b, out);
}

// Round 6
// 158.064 us; speedup vs baseline: 1.1901x; 1.0035x over previous
//
#include <hip/hip_runtime.h>

// Problem constants (fixed by reference)
#define CI    16
#define CO    16
#define HID   256
#define KPAD  288    // 256 + 32; k==256 row carries b2 (VALU-free bias), rest 0
#define NKK   9      // KPAD/32 MFMA K-steps (B side; W2b layout)
#define NKH   8      // kk frags held in LDS (kk=8 pad frag synthesized in regs)
#define NCH   144    // CI*9 columns per output channel
#define IMGH  128
#define IMGW  128
#define RSTR  132    // shPatch row stride in SHORTS (264 B, 8B-aligned)
#define RLEN  130    // valid window px per row: 128 + 2 halo
#define KKSTR (NCH * 32)        // shorts per kk block  = 4608
#define OSTRS (NKK * NCH * 32)  // shorts per o         = 41472
#define MGOFF (4 * NKH * 512)   // shHf shorts per m-group = 16384

typedef float f32x4  __attribute__((ext_vector_type(4)));
typedef float f32x2  __attribute__((ext_vector_type(2)));
typedef short bf16x8 __attribute__((ext_vector_type(8)));

__device__ __host__ __forceinline__ short f2bf(float f) {
  union { float f; unsigned u; } c; c.f = f;
  unsigned b = c.u + 0x7FFFu + ((c.u >> 16) & 1u);   // RNE
  return (short)(b >> 16);
}

// ---------------------------------------------------------------------------
// Prep: W2 [256][2304] fp32 (+ b2[2304]) -> W2b [o][kk:9][n':144][k:32] bf16,
// K padded to 288 (row 256 = b2, rows 257..287 = 0).
// n-columns permuted dx-MAJOR: n' = dx*48 + i*3 + dyr -> dx is uniform per
// 16-wide n-tile, so the main kernel's patch contraction reads an aligned
// window with a per-pass constant shift. Contraction sums over n: order free.
// grid = 36 col-blocks * 9 kk = 324 blocks x 256 threads.
// ---------------------------------------------------------------------------
__global__ void prep_w2(const float* __restrict__ W2, const float* __restrict__ b2,
                        short* __restrict__ W2b) {
  __shared__ float tile[32][65];
  const int kk = blockIdx.x % NKK;
  const int colbase = (blockIdx.x / NKK) * 64;
  const int tid = threadIdx.x;

  for (int e = tid; e < 2048; e += 256) {
    int klr = e >> 6;          // 0..31
    int cc  = e & 63;
    int col = colbase + cc;
    float v;
    if (kk < 8) v = W2[(kk * 32 + klr) * (CO * NCH) + col];
    else        v = (klr == 0) ? b2[col] : 0.f;
    tile[klr][cc] = v;
  }
  __syncthreads();
  for (int e = tid; e < 2048; e += 256) {
    int cc = e >> 5;           // 0..63
    int kl = e & 31;
    int col = colbase + cc;
    int o = col / NCH;
    int n = col - o * NCH;
    int i = n / 9, q = n - i * 9;
    int dyr = q / 3, dx = q - dyr * 3;
    int np = dx * 48 + i * 3 + dyr;            // dx-major permutation
    W2b[(((o * NKK + kk) * NCH + np) << 5) + kl] = f2bf(tile[kl][cc]);
  }
}

// ---------------------------------------------------------------------------
// Main fused kernel, v17 = v16 (N-block of 2 channels, halved A-reads,
// clean full-row writes) MINUS its in-loop barriers.
// Post-mortem v16 (103.3 us vs v14's 96.7): the 8 per-sweep __syncthreads
// forced 4-wave lockstep + pipeline drain 8x per block (~2k cyc/CU each) —
// that ate the entire A-read saving. WRITE did drop 12.4->4.1 MB (staged
// full-row flush works) and FETCH 15.5->11.4 MB.
// v17: carry the 8 per-(sweep,channel) tree results in REGISTERS (Pout[8]);
// no barriers inside the sweep loop. At the end: one barrier, stage all
// 16 rows into REUSED shHf space (dead after last K-sweep; 8 KB of 64 KB),
// one barrier, flush as full 512B rows with float4 stores. 3 barriers
// total (was 9), zero extra LDS (78.3 KB -> 2 blocks/CU).
// Wave = (wo=wv>>1, mg=wv&1): mg owns 64 px (4 ms-tiles), wo owns 8
// channels in 4 sweeps of 2. Per kk-step: 4 A-reads feed 24 MFMAs; epilogue
// patch unpack shared across the channel pair.
// grid = 4 batches * 128 rows = 512 blocks x 256 threads.
// ---------------------------------------------------------------------------
__global__ __launch_bounds__(256, 2)
void ngconv_main(const float* __restrict__ in, const float* __restrict__ foa,
                 const float* __restrict__ W1, const float* __restrict__ b1,
                 const short* __restrict__ W2b, float* __restrict__ out) {
  __shared__ __align__(16) short shHf[64 * 512];  // 64 frags = 64 KB; reused as out-staging
  __shared__ short shPatch[48 * RSTR];            // raw rows [i*3+dyr][xx] bf16, 12.4 KB

  const int tid  = threadIdx.x;
  const int lane = tid & 63;
  const int wv   = tid >> 6;        // 0..3
  const int wo   = wv >> 1;         // channel group: o in [wo*8, wo*8+8)
  const int mg   = wv & 1;          // m-group: px 0..63 or 64..127
  const int c15  = lane & 15;
  const int quad = lane >> 4;

  const int blk = blockIdx.x;
  const int b   = blk >> 7;
  const int y   = blk & 127;

  const float fx  = foa[b * 2 + 0];
  const float fy  = foa[b * 2 + 1];
  const float dyv = (float)y - fy;

  const int ry0 = (y == 0) ? 1 : (y - 1);
  const int ry2 = (y == IMGH - 1) ? (IMGH - 2) : (y + 1);

  // ---- shPatch[r=i*3+dyr][xx]: reflect-extended row, xx in [0,130) maps to
  // image x = xx - 1. Patch value for (n'=(dx,i,dyr), px) = row[px+dx].
  for (int e = tid; e < 48 * RLEN; e += 256) {
    int r  = e / RLEN;                // 0..47 = i*3 + dyr
    int xx = e - r * RLEN;
    int i = r / 3, dyr = r - i * 3;
    int ryr = (dyr == 0) ? ry0 : ((dyr == 1) ? y : ry2);
    int x = xx - 1;
    x = (x < 0) ? 1 : ((x > IMGW - 1) ? (IMGW - 2) : x);   // reflect
    shPatch[r * RSTR + xx] = f2bf(in[((b * CI + i) * IMGH + ryr) * IMGW + x]);
  }

  // ---- shHf: H in fragment order, kk=0..7. frag(ms,kk) = A[16px][32k];
  // lane slot (c15=px, quad=k-octet). 128 px x 32 k-slots = 4096 = 16 exact its.
  for (int g = tid; g < 128 * 32; g += 256) {
    int px = g & 127;
    int ks = g >> 7;                  // 0..31 -> k0 = ks*8 < 256
    int k0 = ks << 3;
    float dxv = (float)px - fx;
    short hv[8];
    #pragma unroll
    for (int j = 0; j < 8; ++j) {
      int k = k0 + j;
      float h = fmaxf(fmaf(dxv, W1[k], fmaf(dyv, W1[HID + k], b1[k])), 0.f);
      hv[j] = f2bf(h);
    }
    int ms = px >> 4;                 // 0..7
    int kk = k0 >> 5;
    int lslot = ((k0 & 31) >> 3) * 16 + (px & 15);   // quad*16 + c15
    *(bf16x8*)&shHf[((ms * NKH + kk) << 9) + (lslot << 3)] = *(bf16x8*)hv;
  }

  // ---- kk=8 pad fragment, constant, in registers: k=256 -> 1.0 (b2 row)
  bf16x8 af8 = (bf16x8){0, 0, 0, 0, 0, 0, 0, 0};
  if (quad == 0) af8[0] = (short)0x3F80;   // bf16 1.0

  __syncthreads();

  // ---- main loop: 4 sweeps of 2 channels per wave; results -> Pout regs
  const short* shHg = shHf + mg * MGOFF;   // this wave's 4 ms-tiles
  float Pout[8];                           // [s*2 + oi]

  #pragma unroll 1
  for (int s = 0; s < 4; ++s) {
    const int o0 = wo * 8 + 2 * s;
    const short* Bo0 = W2b + o0 * OSTRS + (c15 << 5) + (quad << 3);

    // per-sweep partial sums [oi][ms*2 + halfword-pair]
    f32x2 P2[2][8];
    #pragma unroll
    for (int oi = 0; oi < 2; ++oi)
      #pragma unroll
      for (int t = 0; t < 8; ++t) P2[oi][t] = (f32x2){0.f, 0.f};

    #pragma unroll 1
    for (int pass = 0; pass < 3; ++pass) {
      const short* Bp0 = Bo0 + (pass * 3) * 512;   // first n-tile, channel o0
      const short* Bp1 = Bp0 + OSTRS;              // channel o0+1
      f32x4 acc[2][4][3];
      #pragma unroll
      for (int oi = 0; oi < 2; ++oi)
        #pragma unroll
        for (int ms = 0; ms < 4; ++ms)
          #pragma unroll
          for (int j = 0; j < 3; ++j)
            acc[oi][ms][j] = (f32x4){0.f, 0.f, 0.f, 0.f};

      // copy-free 2-buffer ping-pong, distance-1 prefetch, explicit tail.
      bf16x8 bE[2][3], bO[2][3];
      #pragma unroll
      for (int j = 0; j < 3; ++j) {
        bE[0][j] = *(const bf16x8*)&Bp0[j << 9];
        bE[1][j] = *(const bf16x8*)&Bp1[j << 9];
      }

      #pragma unroll 1
      for (int t = 0; t < 4; ++t) {
        const int kkE = 2 * t;            // even kk, uses bE
        #pragma unroll
        for (int j = 0; j < 3; ++j) {     // prefetch odd kk into bO
          bO[0][j] = *(const bf16x8*)&Bp0[(kkE + 1) * KKSTR + (j << 9)];
          bO[1][j] = *(const bf16x8*)&Bp1[(kkE + 1) * KKSTR + (j << 9)];
        }
        {
          const short* hp = shHg + (kkE << 9) + (lane << 3);
          #pragma unroll
          for (int ms = 0; ms < 4; ++ms) {
            bf16x8 af = *(const bf16x8*)&hp[ms * (NKH << 9)];
            #pragma unroll
            for (int oi = 0; oi < 2; ++oi)
              #pragma unroll
              for (int j = 0; j < 3; ++j)
                acc[oi][ms][j] = __builtin_amdgcn_mfma_f32_16x16x32_bf16(
                    af, bE[oi][j], acc[oi][ms][j], 0, 0, 0);
          }
        }
        #pragma unroll
        for (int j = 0; j < 3; ++j) {     // prefetch next even kk into bE
          bE[0][j] = *(const bf16x8*)&Bp0[(kkE + 2) * KKSTR + (j << 9)];
          bE[1][j] = *(const bf16x8*)&Bp1[(kkE + 2) * KKSTR + (j << 9)];
        }
        {
          const short* hp = shHg + ((kkE + 1) << 9) + (lane << 3);
          #pragma unroll
          for (int ms = 0; ms < 4; ++ms) {
            bf16x8 af = *(const bf16x8*)&hp[ms * (NKH << 9)];
            #pragma unroll
            for (int oi = 0; oi < 2; ++oi)
              #pragma unroll
              for (int j = 0; j < 3; ++j)
                acc[oi][ms][j] = __builtin_amdgcn_mfma_f32_16x16x32_bf16(
                    af, bO[oi][j], acc[oi][ms][j], 0, 0, 0);
          }
        }
      }
      {   // tail kk=8 (b2 K-row): af8 from registers, B already in bE
        #pragma unroll
        for (int ms = 0; ms < 4; ++ms)
          #pragma unroll
          for (int oi = 0; oi < 2; ++oi)
            #pragma unroll
            for (int j = 0; j < 3; ++j)
              acc[oi][ms][j] = __builtin_amdgcn_mfma_f32_16x16x32_bf16(
                  af8, bE[oi][j], acc[oi][ms][j], 0, 0, 0);
      }

      // ---- per-pass patch contraction into P2 (b2 already in acc).
      // n' = (pass*3+j)*16 + c15 is dx-major: dx == pass (wave-uniform),
      // row index = 16*j + c15, window = row[mg*64 + ms*16 + quad*4 + dx ..].
      // Patch value is o-INDEPENDENT: one read+unpack serves both channels.
      const int sh = pass << 4;          // 0 / 16 / 32 bits
      #pragma unroll
      for (int j = 0; j < 3; ++j) {
        const short* prow = &shPatch[((j << 4) + c15) * RSTR + (mg << 6) + (quad << 2)];
        #pragma unroll
        for (int ms = 0; ms < 4; ++ms) {
          uint2 u0 = *(const uint2*)&prow[ms * 16];           // ds_read_b64
          unsigned u1 = *(const unsigned*)&prow[ms * 16 + 4]; // ds_read_b32
          unsigned long long a0 =
              (unsigned long long)u0.x | ((unsigned long long)u0.y << 32);
          unsigned long long a1 =
              (unsigned long long)u0.y | ((unsigned long long)u1 << 32);
          unsigned d0 = (unsigned)(a0 >> sh);                // taps r=0,1
          unsigned d1 = (unsigned)(a1 >> sh);                // taps r=2,3
          float p0 = __uint_as_float(d0 << 16);
          float p1 = __uint_as_float(d0 & 0xFFFF0000u);
          float p2 = __uint_as_float(d1 << 16);
          float p3 = __uint_as_float(d1 & 0xFFFF0000u);
          #pragma unroll
          for (int oi = 0; oi < 2; ++oi) {
            f32x2 a01 = {acc[oi][ms][j][0], acc[oi][ms][j][1]};
            f32x2 a23 = {acc[oi][ms][j][2], acc[oi][ms][j][3]};
            P2[oi][ms * 2 + 0] += a01 * (f32x2){p0, p1};     // v_pk_fma_f32
            P2[oi][ms * 2 + 1] += a23 * (f32x2){p2, p3};
          }
        }
      }
    }

    // ---- reduce-scatter tree per channel -> registers (NO barrier here)
    #pragma unroll
    for (int oi = 0; oi < 2; ++oi) {
      float P[16];
      #pragma unroll
      for (int t = 0; t < 16; ++t) P[t] = P2[oi][t >> 1][t & 1];
      #pragma unroll
      for (int m = 8; m >= 1; m >>= 1) {
        const bool hi = (c15 & m) != 0;
        #pragma unroll
        for (int j = 0; j < m; ++j) {
          float keep = hi ? P[j + m] : P[j];
          float send = hi ? P[j] : P[j + m];
          float recv = __shfl_xor(send, m, 64);
          P[j] = keep + recv;
        }
      }
      Pout[s * 2 + oi] = P[0];
    }
  }

  // ---- single staged flush: reuse shHf (dead) as [16][128] f32 = 8 KB
  __syncthreads();                        // all K-loop LDS reads complete
  float* shO = (float*)shHf;
  const int pxw = (mg << 6) + (c15 >> 2) * 16 + quad * 4 + (c15 & 3);
  #pragma unroll
  for (int s = 0; s < 4; ++s)
    #pragma unroll
    for (int oi = 0; oi < 2; ++oi)
      shO[(wo * 8 + 2 * s + oi) * IMGW + pxw] = Pout[s * 2 + oi];
  __syncthreads();
  #pragma unroll
  for (int u = 0; u < 2; ++u) {           // 512 float4s, 2 per thread
    int f   = u * 256 + tid;
    int row = f >> 5;                     // output channel 0..15
    int c4  = f & 31;
    float4 v = *(const float4*)&shO[row * IMGW + c4 * 4];
    *(float4*)&out[((b * CO + row) * IMGH + y) * IMGW + c4 * 4] = v;
  }
}

// ---------------------------------------------------------------------------
extern "C" void kernel_launch(void* const* d_in, const int* in_sizes, int n_in,
                              void* d_out, int out_size, void* d_ws, size_t ws_size,
                              hipStream_t stream) {
  const float* in  = (const float*)d_in[0];   // [4,16,128,128]
  const float* foa = (const float*)d_in[1];   // [4,2]
  const float* W1  = (const float*)d_in[2];   // [2,256]
  const float* b1  = (const float*)d_in[3];   // [256]
  const float* W2  = (const float*)d_in[4];   // [256,2304]
  const float* b2  = (const float*)d_in[5];   // [2304]
  float* out = (float*)d_out;
  short* W2b = (short*)d_ws;                  // 16*9*144*32 bf16 = 1.33 MB

  prep_w2<<<324, 256, 0, stream>>>(W2, b2, W2b);
  ngconv_main<<<512, 256, 0, stream>>>(in, foa, W1, b1, W2b, out);
}